// Round 2
// baseline (1067.730 us; speedup 1.0000x reference)
//
#include <hip/hip_runtime.h>

// Problem constants (fixed by reference)
#define T     4
#define WQ    75
#define WS    25
#define C     640
#define HW    100
#define WAY   5
#define SHOT  5

// Tiling
#define CT    128          // c-tile edge
#define NT    5            // C / CT
#define NPAIR 15           // NT*(NT+1)/2 upper-tri tile pairs
#define KC    20           // k-chunk (LDS depth) -- 20 keeps LDS ~22KB -> 4 blocks/CU
#define LS    132          // LDS row stride in floats
#define QC    5            // queries per block in score kernel (900 blocks, all co-resident)

// ws layout (bytes):
//   cov   : [0, 32768000)            20 * 640*640 * 4   (Cov/99, upper tiles valid)
//   qmean : [32768000, 33536000)     300 * 640 * 4
//   smean : [33536000, 33587200)     20 * 640 * 4
#define WS_COV_OFF   0
#define WS_QMEAN_OFF 32768000
#define WS_SMEAN_OFF 33536000

__device__ __forceinline__ void pair_ij(int p, int& ti, int& tj) {
    int base = 0;
    #pragma unroll
    for (int a = 0; a < NT; ++a) {
        int cnt = NT - a;
        if (p < base + cnt) { ti = a; tj = a + (p - base); return; }
        base += cnt;
    }
    ti = 0; tj = 0;
}

__global__ void init_out_kernel(float* __restrict__ out, const float* __restrict__ bias) {
    int i = blockIdx.x * blockDim.x + threadIdx.x;
    if (i < T * WQ * WAY) out[i] = bias[0];
}

// qmean[t,q,c] over hw ; smean[t,w,c] over shot*hw
__global__ void means_kernel(const float* __restrict__ qf, const float* __restrict__ sf,
                             float* __restrict__ qmean, float* __restrict__ smean) {
    int i = blockIdx.x * blockDim.x + threadIdx.x;
    if (i < T * WQ * C) {
        const float4* p = (const float4*)(qf + (size_t)i * HW);
        float acc = 0.f;
        #pragma unroll
        for (int f = 0; f < HW / 4; ++f) { float4 v = p[f]; acc += v.x + v.y + v.z + v.w; }
        qmean[i] = acc * (1.0f / HW);
    } else if (i < T * WQ * C + T * WAY * C) {
        int j = i - T * WQ * C;
        int c = j % C; int tw = j / C;      // tw = t*WAY + w
        float acc = 0.f;
        for (int sh = 0; sh < SHOT; ++sh) {
            const float4* p = (const float4*)(sf + ((size_t)(tw * SHOT + sh) * C + c) * HW);
            #pragma unroll
            for (int f = 0; f < HW / 4; ++f) { float4 v = p[f]; acc += v.x + v.y + v.z + v.w; }
        }
        smean[j] = acc * (1.0f / (SHOT * HW));
    }
}

// Cov'[t,w] = (Sc^T Sc)/99 for upper 128x128 tile pairs. grid = (NPAIR, T*WAY)
__global__ __launch_bounds__(256, 4)
void cov_kernel(const float* __restrict__ sf, const float* __restrict__ smean,
                float* __restrict__ cov) {
    __shared__ float As[KC][LS];
    __shared__ float Bs[KC][LS];
    __shared__ float smA[CT];
    __shared__ float smB[CT];

    int p  = blockIdx.x;
    int tw = blockIdx.y;                 // t*WAY + w
    int ti, tj; pair_ij(p, ti, tj);
    int tid = threadIdx.x;
    int tx = tid & 15, ty = tid >> 4;

    if (tid < CT) smA[tid] = smean[tw * C + ti * CT + tid];
    else          smB[tid - CT] = smean[tw * C + tj * CT + (tid - CT)];

    float acc[8][8] = {};
    int row = tid & (CT - 1);            // constant per thread across staging iters
    for (int sh = 0; sh < SHOT; ++sh) {
        const float* baseA = sf + ((size_t)(tw * SHOT + sh) * C + ti * CT) * HW;
        const float* baseB = sf + ((size_t)(tw * SHOT + sh) * C + tj * CT) * HW;
        for (int kc = 0; kc < HW; kc += KC) {
            __syncthreads();             // also orders smA/smB on first pass
            float ma = smA[row], mb = smB[row];
            #pragma unroll
            for (int it = 0; it < CT * (KC / 2) / 256; ++it) {
                int f  = tid + it * 256;
                int fi = f >> 7;         // 0..KC/2-1
                int n  = kc + fi * 2;
                float2 va = *(const float2*)(baseA + row * HW + n);
                As[fi * 2 + 0][row] = va.x - ma;
                As[fi * 2 + 1][row] = va.y - ma;
                float2 vb = *(const float2*)(baseB + row * HW + n);
                Bs[fi * 2 + 0][row] = vb.x - mb;
                Bs[fi * 2 + 1][row] = vb.y - mb;
            }
            __syncthreads();
            #pragma unroll 4
            for (int k = 0; k < KC; ++k) {
                // split 4+4 frags: conflict-free (2 lanes/bank max)
                float4 a0 = *(const float4*)&As[k][ty * 4];
                float4 a1 = *(const float4*)&As[k][64 + ty * 4];
                float4 b0 = *(const float4*)&Bs[k][tx * 4];
                float4 b1 = *(const float4*)&Bs[k][64 + tx * 4];
                float a[8] = {a0.x, a0.y, a0.z, a0.w, a1.x, a1.y, a1.z, a1.w};
                float b[8] = {b0.x, b0.y, b0.z, b0.w, b1.x, b1.y, b1.z, b1.w};
                #pragma unroll
                for (int r = 0; r < 8; ++r)
                    #pragma unroll
                    for (int s = 0; s < 8; ++s)
                        acc[r][s] += a[r] * b[s];
            }
        }
    }

    const float inv = 1.0f / (HW - 1);
    float* cb = cov + (size_t)tw * C * C + (size_t)(ti * CT) * C + tj * CT;
    #pragma unroll
    for (int r = 0; r < 8; ++r) {
        int rr = (r < 4) ? (ty * 4 + r) : (64 + ty * 4 + (r - 4));
        float* rp = cb + (size_t)rr * C;
        float4 o0 = {acc[r][0] * inv, acc[r][1] * inv, acc[r][2] * inv, acc[r][3] * inv};
        float4 o1 = {acc[r][4] * inv, acc[r][5] * inv, acc[r][6] * inv, acc[r][7] * inv};
        *(float4*)(rp + tx * 4)      = o0;
        *(float4*)(rp + 64 + tx * 4) = o1;
    }
}

// Fused: M_tq tile (weighted centered Gram of query) dotted with 5 Cov tiles.
// grid = (NPAIR, T, WQ/QC); score[t,q,w] += mult * <Cov_tile, M_tile>
__global__ __launch_bounds__(256, 4)
void score_kernel(const float* __restrict__ qf, const float* __restrict__ qmean,
                  const float* __restrict__ cov, const float* __restrict__ convw,
                  float* __restrict__ out) {
    __shared__ float As[KC][LS];
    __shared__ float Bs[KC][LS];
    __shared__ float wl[HW];
    __shared__ float qmA[CT];
    __shared__ float qmB[CT];
    __shared__ float red[4][WAY];

    int p  = blockIdx.x;
    int t  = blockIdx.y;
    int qc = blockIdx.z;
    int ti, tj; pair_ij(p, ti, tj);
    int tid = threadIdx.x;
    int tx = tid & 15, ty = tid >> 4;
    int lane = tid & 63, wv = tid >> 6;

    if (tid < HW) wl[tid] = convw[tid];
    float mult = (ti == tj) ? 1.0f : 2.0f;
    int row = tid & (CT - 1);

    for (int qi = 0; qi < QC; ++qi) {
        int q = qc * QC + qi;
        __syncthreads();                 // protect qmA/qmB/red from previous iter
        if (tid < CT) qmA[tid] = qmean[(size_t)(t * WQ + q) * C + ti * CT + tid];
        else          qmB[tid - CT] = qmean[(size_t)(t * WQ + q) * C + tj * CT + (tid - CT)];

        float acc[8][8] = {};
        const float* baseA = qf + ((size_t)(t * WQ + q) * C + ti * CT) * HW;
        const float* baseB = qf + ((size_t)(t * WQ + q) * C + tj * CT) * HW;
        for (int kc = 0; kc < HW; kc += KC) {
            __syncthreads();
            float ma = qmA[row], mb = qmB[row];
            #pragma unroll
            for (int it = 0; it < CT * (KC / 2) / 256; ++it) {
                int f  = tid + it * 256;
                int fi = f >> 7;
                int n  = kc + fi * 2;
                float2 va = *(const float2*)(baseA + row * HW + n);
                As[fi * 2 + 0][row] = (va.x - ma) * wl[n];
                As[fi * 2 + 1][row] = (va.y - ma) * wl[n + 1];
                float2 vb = *(const float2*)(baseB + row * HW + n);
                Bs[fi * 2 + 0][row] = vb.x - mb;
                Bs[fi * 2 + 1][row] = vb.y - mb;
            }
            __syncthreads();
            #pragma unroll 4
            for (int k = 0; k < KC; ++k) {
                float4 a0 = *(const float4*)&As[k][ty * 4];
                float4 a1 = *(const float4*)&As[k][64 + ty * 4];
                float4 b0 = *(const float4*)&Bs[k][tx * 4];
                float4 b1 = *(const float4*)&Bs[k][64 + tx * 4];
                float a[8] = {a0.x, a0.y, a0.z, a0.w, a1.x, a1.y, a1.z, a1.w};
                float b[8] = {b0.x, b0.y, b0.z, b0.w, b1.x, b1.y, b1.z, b1.w};
                #pragma unroll
                for (int r = 0; r < 8; ++r)
                    #pragma unroll
                    for (int s = 0; s < 8; ++s)
                        acc[r][s] += a[r] * b[s];
            }
        }

        // Dot the in-register M tile with the 5 ways' Cov tiles (L2/L3-resident)
        float sums[WAY];
        const float* cb0 = cov + (size_t)(t * WAY) * C * C
                         + (size_t)(ti * CT) * C + tj * CT;
        #pragma unroll
        for (int w = 0; w < WAY; ++w) {
            const float* cb = cb0 + (size_t)w * C * C;
            float s = 0.f;
            #pragma unroll
            for (int r = 0; r < 8; ++r) {
                int rr = (r < 4) ? (ty * 4 + r) : (64 + ty * 4 + (r - 4));
                const float* rp = cb + (size_t)rr * C;
                float4 c0 = *(const float4*)(rp + tx * 4);
                float4 c1 = *(const float4*)(rp + 64 + tx * 4);
                s += acc[r][0] * c0.x + acc[r][1] * c0.y + acc[r][2] * c0.z + acc[r][3] * c0.w
                   + acc[r][4] * c1.x + acc[r][5] * c1.y + acc[r][6] * c1.z + acc[r][7] * c1.w;
            }
            sums[w] = s * mult;
        }

        #pragma unroll
        for (int w = 0; w < WAY; ++w) {
            float v = sums[w];
            #pragma unroll
            for (int off = 32; off > 0; off >>= 1) v += __shfl_down(v, off);
            if (lane == 0) red[wv][w] = v;
        }
        __syncthreads();
        if (tid < WAY) {
            float tot = red[0][tid] + red[1][tid] + red[2][tid] + red[3][tid];
            atomicAdd(&out[(size_t)(t * WQ + q) * WAY + tid], tot);
        }
    }
}

extern "C" void kernel_launch(void* const* d_in, const int* in_sizes, int n_in,
                              void* d_out, int out_size, void* d_ws, size_t ws_size,
                              hipStream_t stream) {
    const float* qf = (const float*)d_in[0];   // (4,75,640,10,10)
    const float* sf = (const float*)d_in[1];   // (4,25,640,10,10)
    const float* cw = (const float*)d_in[2];   // (1,1,100)
    const float* cb = (const float*)d_in[3];   // (1,)
    float* out = (float*)d_out;                // (4,75,5)

    float* cov   = (float*)((char*)d_ws + WS_COV_OFF);
    float* qmean = (float*)((char*)d_ws + WS_QMEAN_OFF);
    float* smean = (float*)((char*)d_ws + WS_SMEAN_OFF);

    init_out_kernel<<<(T * WQ * WAY + 255) / 256, 256, 0, stream>>>(out, cb);
    means_kernel<<<(T * WQ * C + T * WAY * C + 255) / 256, 256, 0, stream>>>(qf, sf, qmean, smean);
    cov_kernel<<<dim3(NPAIR, T * WAY), 256, 0, stream>>>(sf, smean, cov);
    score_kernel<<<dim3(NPAIR, T, WQ / QC), 256, 0, stream>>>(qf, qmean, cov, cw, out);
}

// Round 3
// 733.286 us; speedup vs baseline: 1.4561x; 1.4561x over previous
//
#include <hip/hip_runtime.h>

// Problem constants (fixed by reference)
#define T     4
#define WQ    75
#define WS    25
#define C     640
#define HW    100
#define WAY   5
#define SHOT  5
#define SHW   (SHOT*HW)    // 500

// Tiling
#define CT    128          // c-tile edge
#define NT    5            // C / CT
#define NPAIR 15           // NT*(NT+1)/2 upper-tri tile pairs
#define KC    20           // k-chunk (LDS depth): As+Bs = 2*20*132*4 = 21.1 KB
#define LS    132          // LDS row stride in floats
#define QC    5            // queries per block in score kernel

// ws layout (bytes)
#define WS_COV_OFF   0            // 20 * 640*640 * 4 = 32,768,000  (Cov/99, upper tiles)
#define WS_QMEAN_OFF 32768000     // 300 * 640 * 4
#define WS_SMEAN_OFF 33536000     // 20 * 640 * 4
#define WS_QT_OFF    33587200     // 300 * 100 * 640 * 4 = 76,800,000 (centered, [n][c])
#define WS_ST_OFF    110387200    // 20 * 500 * 640 * 4 = 25,600,000 (centered, [m][c])

__device__ __forceinline__ void pair_ij(int p, int& ti, int& tj) {
    int base = 0;
    #pragma unroll
    for (int a = 0; a < NT; ++a) {
        int cnt = NT - a;
        if (p < base + cnt) { ti = a; tj = a + (p - base); return; }
        base += cnt;
    }
    ti = 0; tj = 0;
}

__global__ void init_out_kernel(float* __restrict__ out, const float* __restrict__ bias) {
    int i = blockIdx.x * blockDim.x + threadIdx.x;
    if (i < T * WQ * WAY) out[i] = bias[0];
}

// qmean[t,q,c] over hw ; smean[t,w,c] over shot*hw  (reads raw [c][hw] layout)
__global__ void means_kernel(const float* __restrict__ qf, const float* __restrict__ sf,
                             float* __restrict__ qmean, float* __restrict__ smean) {
    int i = blockIdx.x * blockDim.x + threadIdx.x;
    if (i < T * WQ * C) {
        const float4* p = (const float4*)(qf + (size_t)i * HW);
        float acc = 0.f;
        #pragma unroll
        for (int f = 0; f < HW / 4; ++f) { float4 v = p[f]; acc += v.x + v.y + v.z + v.w; }
        qmean[i] = acc * (1.0f / HW);
    } else if (i < T * WQ * C + T * WAY * C) {
        int j = i - T * WQ * C;
        int c = j % C; int tw = j / C;
        float acc = 0.f;
        for (int sh = 0; sh < SHOT; ++sh) {
            const float4* p = (const float4*)(sf + ((size_t)(tw * SHOT + sh) * C + c) * HW);
            #pragma unroll
            for (int f = 0; f < HW / 4; ++f) { float4 v = p[f]; acc += v.x + v.y + v.z + v.w; }
        }
        smean[j] = acc * (1.0f / (SHOT * HW));
    }
}

// Transpose + center: qt[tq][n][c] = qf[tq][c][n] - qmean ; st[tw][sh*100+n][c] likewise.
// grid = (C/64, 300+100), block 256. LDS tile 64c x 100n.
__global__ __launch_bounds__(256)
void transpose_kernel(const float* __restrict__ qf, const float* __restrict__ sf,
                      const float* __restrict__ qmean, const float* __restrict__ smean,
                      float* __restrict__ qt, float* __restrict__ st) {
    __shared__ float tr[HW][65];
    int c0 = blockIdx.x * 64;
    int by = blockIdx.y;
    const float* src; const float* mean; float* dst;
    if (by < T * WQ) {
        src  = qf + (size_t)by * C * HW;
        mean = qmean + (size_t)by * C;
        dst  = qt + (size_t)by * HW * C;
    } else {
        int idx = by - T * WQ;
        int tw = idx / SHOT, sh = idx % SHOT;
        src  = sf + (size_t)(tw * SHOT + sh) * C * HW;
        mean = smean + (size_t)tw * C;
        dst  = st + ((size_t)tw * SHW + sh * HW) * C;
    }
    int tid = threadIdx.x;
    #pragma unroll
    for (int it = 0; it < 25; ++it) {
        int idx = tid + it * 256;
        int c = idx / HW, n = idx % HW;
        tr[n][c] = src[(size_t)(c0 + c) * HW + n] - mean[c0 + c];
    }
    __syncthreads();
    #pragma unroll
    for (int it = 0; it < 25; ++it) {
        int idx = tid + it * 256;
        int n = idx >> 6, c = idx & 63;
        dst[(size_t)n * C + c0 + c] = tr[n][c];
    }
}

// Cov'[t,w] = (Sc^T Sc)/99 from centered st[tw][m][c]. grid = (NPAIR, T*WAY)
__global__ __launch_bounds__(256, 2)
void cov_kernel(const float* __restrict__ st, float* __restrict__ cov) {
    __shared__ float As[KC][LS];
    __shared__ float Bs[KC][LS];

    int p  = blockIdx.x;
    int tw = blockIdx.y;
    int ti, tj; pair_ij(p, ti, tj);
    int tid = threadIdx.x;
    int tx = tid & 15, ty = tid >> 4;
    int r4 = tid >> 6, ln = tid & 63;

    const float* base = st + (size_t)tw * SHW * C;
    float acc[8][8] = {};
    for (int mc = 0; mc < SHW; mc += KC) {
        __syncthreads();
        #pragma unroll
        for (int i = 0; i < KC / 4; ++i) {
            int k = i * 4 + r4;
            const float* rp = base + (size_t)(mc + k) * C;
            float2 va = *(const float2*)(rp + ti * CT + ln * 2);
            float2 vb = *(const float2*)(rp + tj * CT + ln * 2);
            As[k][ln * 2] = va.x; As[k][ln * 2 + 1] = va.y;
            Bs[k][ln * 2] = vb.x; Bs[k][ln * 2 + 1] = vb.y;
        }
        __syncthreads();
        #pragma unroll 4
        for (int k = 0; k < KC; ++k) {
            float4 a0 = *(const float4*)&As[k][ty * 4];
            float4 a1 = *(const float4*)&As[k][64 + ty * 4];
            float4 b0 = *(const float4*)&Bs[k][tx * 4];
            float4 b1 = *(const float4*)&Bs[k][64 + tx * 4];
            float a[8] = {a0.x, a0.y, a0.z, a0.w, a1.x, a1.y, a1.z, a1.w};
            float b[8] = {b0.x, b0.y, b0.z, b0.w, b1.x, b1.y, b1.z, b1.w};
            #pragma unroll
            for (int r = 0; r < 8; ++r)
                #pragma unroll
                for (int s = 0; s < 8; ++s)
                    acc[r][s] += a[r] * b[s];
        }
    }

    const float inv = 1.0f / (HW - 1);
    float* cb = cov + (size_t)tw * C * C + (size_t)(ti * CT) * C + tj * CT;
    #pragma unroll
    for (int r = 0; r < 8; ++r) {
        int rr = (r < 4) ? (ty * 4 + r) : (64 + ty * 4 + (r - 4));
        float* rp = cb + (size_t)rr * C;
        float4 o0 = {acc[r][0] * inv, acc[r][1] * inv, acc[r][2] * inv, acc[r][3] * inv};
        float4 o1 = {acc[r][4] * inv, acc[r][5] * inv, acc[r][6] * inv, acc[r][7] * inv};
        *(float4*)(rp + tx * 4)      = o0;
        *(float4*)(rp + 64 + tx * 4) = o1;
    }
}

// Fused: weighted centered query Gram tile dotted with 5 Cov tiles.
// grid = (NPAIR, T, WQ/QC); score[t,q,w] += mult * <Cov_tile, M_tile>
__global__ __launch_bounds__(256, 2)
void score_kernel(const float* __restrict__ qt, const float* __restrict__ cov,
                  const float* __restrict__ convw, float* __restrict__ out) {
    __shared__ float As[KC][LS];
    __shared__ float Bs[KC][LS];
    __shared__ float wl[HW];
    __shared__ float red[4][WAY];

    int p  = blockIdx.x;
    int t  = blockIdx.y;
    int qc = blockIdx.z;
    int ti, tj; pair_ij(p, ti, tj);
    int tid = threadIdx.x;
    int tx = tid & 15, ty = tid >> 4;
    int r4 = tid >> 6, ln = tid & 63;
    int lane = tid & 63, wv = tid >> 6;

    if (tid < HW) wl[tid] = convw[tid];
    float mult = (ti == tj) ? 1.0f : 2.0f;

    for (int qi = 0; qi < QC; ++qi) {
        int q = qc * QC + qi;
        const float* qb = qt + (size_t)(t * WQ + q) * HW * C;

        float acc[8][8] = {};
        for (int kc = 0; kc < HW; kc += KC) {
            __syncthreads();             // also orders wl on first pass, red reuse
            #pragma unroll
            for (int i = 0; i < KC / 4; ++i) {
                int k = i * 4 + r4;
                int n = kc + k;
                const float* rp = qb + (size_t)n * C;
                float2 va = *(const float2*)(rp + ti * CT + ln * 2);
                float2 vb = *(const float2*)(rp + tj * CT + ln * 2);
                float w = wl[n];
                As[k][ln * 2] = va.x * w; As[k][ln * 2 + 1] = va.y * w;
                Bs[k][ln * 2] = vb.x;     Bs[k][ln * 2 + 1] = vb.y;
            }
            __syncthreads();
            #pragma unroll 4
            for (int k = 0; k < KC; ++k) {
                float4 a0 = *(const float4*)&As[k][ty * 4];
                float4 a1 = *(const float4*)&As[k][64 + ty * 4];
                float4 b0 = *(const float4*)&Bs[k][tx * 4];
                float4 b1 = *(const float4*)&Bs[k][64 + tx * 4];
                float a[8] = {a0.x, a0.y, a0.z, a0.w, a1.x, a1.y, a1.z, a1.w};
                float b[8] = {b0.x, b0.y, b0.z, b0.w, b1.x, b1.y, b1.z, b1.w};
                #pragma unroll
                for (int r = 0; r < 8; ++r)
                    #pragma unroll
                    for (int s = 0; s < 8; ++s)
                        acc[r][s] += a[r] * b[s];
            }
        }

        // Dot in-register M tile with the 5 ways' Cov tiles (L2/L3-resident)
        float sums[WAY];
        const float* cb0 = cov + (size_t)(t * WAY) * C * C
                         + (size_t)(ti * CT) * C + tj * CT;
        #pragma unroll
        for (int w = 0; w < WAY; ++w) {
            const float* cb = cb0 + (size_t)w * C * C;
            float s = 0.f;
            #pragma unroll
            for (int r = 0; r < 8; ++r) {
                int rr = (r < 4) ? (ty * 4 + r) : (64 + ty * 4 + (r - 4));
                const float* rp = cb + (size_t)rr * C;
                float4 c0 = *(const float4*)(rp + tx * 4);
                float4 c1 = *(const float4*)(rp + 64 + tx * 4);
                s += acc[r][0] * c0.x + acc[r][1] * c0.y + acc[r][2] * c0.z + acc[r][3] * c0.w
                   + acc[r][4] * c1.x + acc[r][5] * c1.y + acc[r][6] * c1.z + acc[r][7] * c1.w;
            }
            sums[w] = s * mult;
        }

        #pragma unroll
        for (int w = 0; w < WAY; ++w) {
            float v = sums[w];
            #pragma unroll
            for (int off = 32; off > 0; off >>= 1) v += __shfl_down(v, off);
            if (lane == 0) red[wv][w] = v;
        }
        __syncthreads();
        if (tid < WAY) {
            float tot = red[0][tid] + red[1][tid] + red[2][tid] + red[3][tid];
            atomicAdd(&out[(size_t)(t * WQ + q) * WAY + tid], tot);
        }
    }
}

extern "C" void kernel_launch(void* const* d_in, const int* in_sizes, int n_in,
                              void* d_out, int out_size, void* d_ws, size_t ws_size,
                              hipStream_t stream) {
    const float* qf = (const float*)d_in[0];   // (4,75,640,10,10)
    const float* sf = (const float*)d_in[1];   // (4,25,640,10,10)
    const float* cw = (const float*)d_in[2];   // (1,1,100)
    const float* cb = (const float*)d_in[3];   // (1,)
    float* out = (float*)d_out;                // (4,75,5)

    float* cov   = (float*)((char*)d_ws + WS_COV_OFF);
    float* qmean = (float*)((char*)d_ws + WS_QMEAN_OFF);
    float* smean = (float*)((char*)d_ws + WS_SMEAN_OFF);
    float* qt    = (float*)((char*)d_ws + WS_QT_OFF);
    float* st    = (float*)((char*)d_ws + WS_ST_OFF);

    init_out_kernel<<<(T * WQ * WAY + 255) / 256, 256, 0, stream>>>(out, cb);
    means_kernel<<<(T * WQ * C + T * WAY * C + 255) / 256, 256, 0, stream>>>(qf, sf, qmean, smean);
    transpose_kernel<<<dim3(C / 64, T * WQ + T * WS), 256, 0, stream>>>(qf, sf, qmean, smean, qt, st);
    cov_kernel<<<dim3(NPAIR, T * WAY), 256, 0, stream>>>(st, cov);
    score_kernel<<<dim3(NPAIR, T, WQ / QC), 256, 0, stream>>>(qt, cov, cw, out);
}

// Round 4
// 693.844 us; speedup vs baseline: 1.5389x; 1.0568x over previous
//
#include <hip/hip_runtime.h>

// Problem constants (fixed by reference)
#define T     4
#define WQ    75
#define C     640
#define HW    100
#define WAY   5
#define SHOT  5
#define SHW   (SHOT*HW)    // 500
#define SPAD  512          // support k padded
#define QPAD  128          // query n padded

// Tiling
#define CT    128
#define NT    5            // C / CT
#define NPAIR 15
#define QC    5            // queries per score block -> grid (15,4,15) = 900 blocks

// ws layout (bytes)
#define WS_COV_OFF   0                 // 20*15*16384*4 = 19,660,800 (fragment-order tiles)
#define WS_QMEAN_OFF 19660800          // 300*640*4 = 768,000
#define WS_SMEAN_OFF 20428800          // 20*640*4  =  51,200
#define WS_QTB_OFF   20480000          // 300*640*128*2 = 49,152,000 (centered bf16)
#define WS_QTBW_OFF  69632000          // 300*640*128*2 = 49,152,000 (centered*convw bf16)
#define WS_STB_OFF   118784000         // 20*640*512*2  = 13,107,200 (centered bf16)

typedef __attribute__((ext_vector_type(8)))  short bfrag8;   // 8 bf16 = 4 VGPRs
typedef __attribute__((ext_vector_type(16))) float f32x16;   // MFMA accumulator

__device__ __forceinline__ unsigned short f2bf(float x) {
    unsigned int u = __float_as_uint(x);
    unsigned int r = (u + 0x7fffu + ((u >> 16) & 1u)) >> 16;   // RNE
    return (unsigned short)r;
}

__device__ __forceinline__ void pair_ij(int p, int& ti, int& tj) {
    int base = 0;
    #pragma unroll
    for (int a = 0; a < NT; ++a) {
        int cnt = NT - a;
        if (p < base + cnt) { ti = a; tj = a + (p - base); return; }
        base += cnt;
    }
    ti = 0; tj = 0;
}

__global__ void init_out_kernel(float* __restrict__ out, const float* __restrict__ bias) {
    int i = blockIdx.x * blockDim.x + threadIdx.x;
    if (i < T * WQ * WAY) out[i] = bias[0];
}

// qmean[t,q,c] over hw ; smean[t,w,c] over shot*hw (reads raw [c][hw] layout, coalesced float4)
__global__ void means_kernel(const float* __restrict__ qf, const float* __restrict__ sf,
                             float* __restrict__ qmean, float* __restrict__ smean) {
    int i = blockIdx.x * blockDim.x + threadIdx.x;
    if (i < T * WQ * C) {
        const float4* p = (const float4*)(qf + (size_t)i * HW);
        float acc = 0.f;
        #pragma unroll
        for (int f = 0; f < HW / 4; ++f) { float4 v = p[f]; acc += v.x + v.y + v.z + v.w; }
        qmean[i] = acc * (1.0f / HW);
    } else if (i < T * WQ * C + T * WAY * C) {
        int j = i - T * WQ * C;
        int c = j % C; int tw = j / C;
        float acc = 0.f;
        for (int sh = 0; sh < SHOT; ++sh) {
            const float4* p = (const float4*)(sf + ((size_t)(tw * SHOT + sh) * C + c) * HW);
            #pragma unroll
            for (int f = 0; f < HW / 4; ++f) { float4 v = p[f]; acc += v.x + v.y + v.z + v.w; }
        }
        smean[j] = acc * (1.0f / (SHOT * HW));
    }
}

// Pack centered bf16 planes: qtb [tq][c][128], qtbw (conv-weighted), stb [tw][c][512]
__global__ void pack_kernel(const float* __restrict__ qf, const float* __restrict__ sf,
                            const float* __restrict__ qmean, const float* __restrict__ smean,
                            const float* __restrict__ convw,
                            unsigned short* __restrict__ qtb, unsigned short* __restrict__ qtbw,
                            unsigned short* __restrict__ stb) {
    long long i = (long long)blockIdx.x * 256 + threadIdx.x;
    const long long NQ = (long long)T * WQ * C * (QPAD / 8);     // 3,072,000
    const long long NS = (long long)T * WAY * C * (SPAD / 8);    //   819,200
    if (i < NQ) {
        int oct = (int)(i & (QPAD / 8 - 1));
        long long r = i >> 4;                    // r = tq*C + c
        float m = qmean[r];
        const float* src = qf + r * HW;
        unsigned short ob[8] __attribute__((aligned(16)));
        unsigned short ow[8] __attribute__((aligned(16)));
        #pragma unroll
        for (int j = 0; j < 8; ++j) {
            int n = oct * 8 + j;
            float v = (n < HW) ? (src[n] - m) : 0.f;
            float w = (n < HW) ? convw[n] : 0.f;
            ob[j] = f2bf(v); ow[j] = f2bf(v * w);
        }
        *(uint4*)(qtb  + r * QPAD + oct * 8) = *(uint4*)ob;
        *(uint4*)(qtbw + r * QPAD + oct * 8) = *(uint4*)ow;
    } else if (i < NQ + NS) {
        long long j2 = i - NQ;
        int oct = (int)(j2 & (SPAD / 8 - 1));
        long long r = j2 >> 6;                   // r = tw*C + c
        int c = (int)(r % C); int tw = (int)(r / C);
        float m = smean[r];
        unsigned short ob[8] __attribute__((aligned(16)));
        #pragma unroll
        for (int j = 0; j < 8; ++j) {
            int mm = oct * 8 + j;
            float v = 0.f;
            if (mm < SHW) {
                int sh = mm / HW, n = mm % HW;
                v = sf[((size_t)(tw * SHOT + sh) * C + c) * HW + n] - m;
            }
            ob[j] = f2bf(v);
        }
        *(uint4*)(stb + r * SPAD + oct * 8) = *(uint4*)ob;
    }
}

// ---- shared MFMA tile helpers (identical structure in cov & score => consistent layout) ----
// LDS chunk layout: 32 k x 128 m, fragment order: seg = s*8 + mb*2 + khalf (16 segs x 512B)
#define STAGE_PAIR(Abase, Bbase, ROWLEN, ch)                                              \
    for (int ii = 0; ii < 2; ++ii) {                                                      \
        int u = tid + ii * 256;                                                           \
        int h8 = u & 3, c = u >> 2;                                                       \
        int seg = ((h8 >> 1) * 8) + ((c >> 5) * 2) + (h8 & 1);                            \
        *(uint4*)&Al[(seg * 32 + (c & 31)) * 8] =                                         \
            *(const uint4*)((Abase) + (size_t)c * (ROWLEN) + (ch) * 32 + h8 * 8);         \
        *(uint4*)&Bl[(seg * 32 + (c & 31)) * 8] =                                         \
            *(const uint4*)((Bbase) + (size_t)c * (ROWLEN) + (ch) * 32 + h8 * 8);         \
    }

#define MFMA_CHUNK()                                                                      \
    _Pragma("unroll")                                                                     \
    for (int s = 0; s < 2; ++s) {                                                         \
        bfrag8 a0 = *(bfrag8*)&Al[(((s * 8) + ((qm * 2 + 0) * 2) + lh) * 32 + ls) * 8];   \
        bfrag8 a1 = *(bfrag8*)&Al[(((s * 8) + ((qm * 2 + 1) * 2) + lh) * 32 + ls) * 8];   \
        bfrag8 b0 = *(bfrag8*)&Bl[(((s * 8) + ((qn * 2 + 0) * 2) + lh) * 32 + ls) * 8];   \
        bfrag8 b1 = *(bfrag8*)&Bl[(((s * 8) + ((qn * 2 + 1) * 2) + lh) * 32 + ls) * 8];   \
        acc[0] = __builtin_amdgcn_mfma_f32_32x32x16_bf16(a0, b0, acc[0], 0, 0, 0);        \
        acc[1] = __builtin_amdgcn_mfma_f32_32x32x16_bf16(a0, b1, acc[1], 0, 0, 0);        \
        acc[2] = __builtin_amdgcn_mfma_f32_32x32x16_bf16(a1, b0, acc[2], 0, 0, 0);        \
        acc[3] = __builtin_amdgcn_mfma_f32_32x32x16_bf16(a1, b1, acc[3], 0, 0, 0);        \
    }

// Cov tiles, written in fragment order: covf[(tw*15+p)*16384 + ((wave*4+b)*4+j)*256 + lane*4 ..]
__global__ __launch_bounds__(256, 3)
void cov_kernel(const unsigned short* __restrict__ stb, float* __restrict__ covf) {
    __shared__ unsigned short Al[4096];
    __shared__ unsigned short Bl[4096];
    int p = blockIdx.x, tw = blockIdx.y;
    int ti, tj; pair_ij(p, ti, tj);
    int tid = threadIdx.x, lane = tid & 63, wave = tid >> 6;
    int qm = wave & 1, qn = wave >> 1, lh = lane >> 5, ls = lane & 31;

    const unsigned short* Abase = stb + ((size_t)tw * C + ti * CT) * SPAD;
    const unsigned short* Bbase = stb + ((size_t)tw * C + tj * CT) * SPAD;

    f32x16 acc[4];
    #pragma unroll
    for (int b = 0; b < 4; ++b)
        #pragma unroll
        for (int e = 0; e < 16; ++e) acc[b][e] = 0.f;

    for (int ch = 0; ch < SPAD / 32; ++ch) {
        __syncthreads();
        STAGE_PAIR(Abase, Bbase, SPAD, ch)
        __syncthreads();
        MFMA_CHUNK()
    }

    const float inv = 1.0f / (HW - 1);
    float* cb = covf + ((size_t)tw * NPAIR + p) * 16384;
    #pragma unroll
    for (int b = 0; b < 4; ++b)
        #pragma unroll
        for (int j = 0; j < 4; ++j) {
            float4 o = { acc[b][4*j] * inv, acc[b][4*j+1] * inv,
                         acc[b][4*j+2] * inv, acc[b][4*j+3] * inv };
            *(float4*)(cb + (size_t)(((wave * 4 + b) * 4 + j) * 64 + lane) * 4) = o;
        }
}

// Fused: MFMA weighted query Gram tile, dot with 5 fragment-order cov tiles.
__global__ __launch_bounds__(256, 3)
void score_kernel(const unsigned short* __restrict__ qtb, const unsigned short* __restrict__ qtbw,
                  const float* __restrict__ covf, float* __restrict__ out) {
    __shared__ unsigned short Al[4096];
    __shared__ unsigned short Bl[4096];
    __shared__ float red[4][WAY];
    int p = blockIdx.x, t = blockIdx.y, qg = blockIdx.z;
    int ti, tj; pair_ij(p, ti, tj);
    int tid = threadIdx.x, lane = tid & 63, wave = tid >> 6;
    int qm = wave & 1, qn = wave >> 1, lh = lane >> 5, ls = lane & 31;
    float mult = (ti == tj) ? 1.0f : 2.0f;

    for (int qi = 0; qi < QC; ++qi) {
        int q = qg * QC + qi;
        const unsigned short* Abase = qtbw + ((size_t)(t * WQ + q) * C + ti * CT) * QPAD;
        const unsigned short* Bbase = qtb  + ((size_t)(t * WQ + q) * C + tj * CT) * QPAD;

        f32x16 acc[4];
        #pragma unroll
        for (int b = 0; b < 4; ++b)
            #pragma unroll
            for (int e = 0; e < 16; ++e) acc[b][e] = 0.f;

        for (int ch = 0; ch < QPAD / 32; ++ch) {
            __syncthreads();             // also protects red[] from previous query
            STAGE_PAIR(Abase, Bbase, QPAD, ch)
            __syncthreads();
            MFMA_CHUNK()
        }

        // Frobenius dot with 5 ways' cov tiles (fragment order => coalesced dwordx4)
        float sums[WAY];
        const float* cb0 = covf + ((size_t)(t * WAY) * NPAIR + p) * 16384;
        #pragma unroll
        for (int w = 0; w < WAY; ++w) {
            const float* cb = cb0 + (size_t)w * NPAIR * 16384;
            float s = 0.f;
            #pragma unroll
            for (int b = 0; b < 4; ++b)
                #pragma unroll
                for (int j = 0; j < 4; ++j) {
                    float4 cv = *(const float4*)(cb + (size_t)(((wave * 4 + b) * 4 + j) * 64 + lane) * 4);
                    s += cv.x * acc[b][4*j]   + cv.y * acc[b][4*j+1]
                       + cv.z * acc[b][4*j+2] + cv.w * acc[b][4*j+3];
                }
            sums[w] = s * mult;
        }

        #pragma unroll
        for (int w = 0; w < WAY; ++w) {
            float v = sums[w];
            #pragma unroll
            for (int off = 32; off > 0; off >>= 1) v += __shfl_down(v, off);
            if (lane == 0) red[wave][w] = v;
        }
        __syncthreads();
        if (tid < WAY) {
            float tot = red[0][tid] + red[1][tid] + red[2][tid] + red[3][tid];
            atomicAdd(&out[(size_t)(t * WQ + q) * WAY + tid], tot);
        }
    }
}

extern "C" void kernel_launch(void* const* d_in, const int* in_sizes, int n_in,
                              void* d_out, int out_size, void* d_ws, size_t ws_size,
                              hipStream_t stream) {
    const float* qf = (const float*)d_in[0];   // (4,75,640,10,10)
    const float* sf = (const float*)d_in[1];   // (4,25,640,10,10)
    const float* cw = (const float*)d_in[2];   // (1,1,100)
    const float* cb = (const float*)d_in[3];   // (1,)
    float* out = (float*)d_out;                // (4,75,5)

    float*          covf  = (float*)((char*)d_ws + WS_COV_OFF);
    float*          qmean = (float*)((char*)d_ws + WS_QMEAN_OFF);
    float*          smean = (float*)((char*)d_ws + WS_SMEAN_OFF);
    unsigned short* qtb   = (unsigned short*)((char*)d_ws + WS_QTB_OFF);
    unsigned short* qtbw  = (unsigned short*)((char*)d_ws + WS_QTBW_OFF);
    unsigned short* stb   = (unsigned short*)((char*)d_ws + WS_STB_OFF);

    init_out_kernel<<<(T * WQ * WAY + 255) / 256, 256, 0, stream>>>(out, cb);
    means_kernel<<<(T * WQ * C + T * WAY * C + 255) / 256, 256, 0, stream>>>(qf, sf, qmean, smean);
    {
        long long total = (long long)T * WQ * C * (QPAD / 8) + (long long)T * WAY * C * (SPAD / 8);
        pack_kernel<<<(int)((total + 255) / 256), 256, 0, stream>>>(qf, sf, qmean, smean, cw,
                                                                    qtb, qtbw, stb);
    }
    cov_kernel<<<dim3(NPAIR, T * WAY), 256, 0, stream>>>(stb, covf);
    score_kernel<<<dim3(NPAIR, T, WQ / QC), 256, 0, stream>>>(qtb, qtbw, covf, out);
}